// Round 18
// baseline (350.437 us; speedup 1.0000x reference)
//
#include <hip/hip_runtime.h>

#define B_  1024
#define T_  128
#define V_  89
#define H_  256
#define NB2 256
#define NPAIR 91136          // B_*V_
#define NW1  1424            // 356*4 loss waves

typedef __attribute__((ext_vector_type(8))) short bf16x8;
typedef __attribute__((ext_vector_type(4))) float f32x4;
typedef __attribute__((ext_vector_type(4))) unsigned short u16x4;
typedef __attribute__((ext_vector_type(8))) int i32x8;
typedef __attribute__((ext_vector_type(4))) int i32x4;

__device__ __forceinline__ short f2bs(float f){
    unsigned u = __float_as_uint(f);
    unsigned r = (u + 0x7FFFu + ((u>>16)&1u)) >> 16;
    return (short)r;
}
__device__ __forceinline__ float s2f(unsigned short s){
    return __uint_as_float(((unsigned)s) << 16);
}
__device__ __forceinline__ float sig_(float x){ return 1.f/(1.f+__expf(-x)); }
__device__ __forceinline__ float tanh_(float x){ return 2.f/(1.f+__expf(-2.f*x)) - 1.f; }
__device__ __forceinline__ void bar_lgkm(){
    asm volatile("s_waitcnt lgkmcnt(0)" ::: "memory");
    __builtin_amdgcn_s_barrier();
}

// ---------------------------------------------------------------- W_hh fp32 -> fp8 [768][256]
__global__ __launch_bounds__(256) void k_cvt_fp8(
    const float* __restrict__ src, unsigned char* __restrict__ dst, int n)
{
    int i = blockIdx.x*256 + threadIdx.x;
    if (i*4 >= n) return;
    float f0 = src[i*4+0], f1 = src[i*4+1], f2 = src[i*4+2], f3 = src[i*4+3];
    int w = __builtin_amdgcn_cvt_pk_fp8_f32(f0, f1, 0, false);
    w     = __builtin_amdgcn_cvt_pk_fp8_f32(f2, f3, w, true);
    ((int*)dst)[i] = w;
}

// ---------------------------------------------------------------- W_ih+b_ih -> fp8 frag-major
// chunk idx = (((WV*3+g)*6+kt)*4+g8)*16+l15; 8 fp8 of row n=g*256+WV*16+l15, k=kt*32+g8*8..+7
// (k: 0..177 = W_ih, 178 = bias, else 0)
__global__ __launch_bounds__(256) void k_prep_wih8(
    const float* __restrict__ W_ih, const float* __restrict__ b_ih,
    unsigned char* __restrict__ dst)
{
    int i = blockIdx.x*256 + threadIdx.x;
    if (i >= 18432) return;
    int l15 = i & 15, t = i >> 4;
    int g8 = t & 3; t >>= 2;
    int kt = t % 6; t /= 6;
    int g = t % 3, WV = t / 3;
    int n = g*256 + WV*16 + l15;
    float f[8];
    #pragma unroll
    for (int j = 0; j < 8; ++j) {
        int k = kt*32 + g8*8 + j;
        f[j] = (k < 178) ? W_ih[(size_t)n*178 + k] : (k == 178 ? b_ih[n] : 0.f);
    }
    int w0 = __builtin_amdgcn_cvt_pk_fp8_f32(f[0], f[1], 0, false);
    w0     = __builtin_amdgcn_cvt_pk_fp8_f32(f[2], f[3], w0, true);
    int w1 = __builtin_amdgcn_cvt_pk_fp8_f32(f[4], f[5], 0, false);
    w1     = __builtin_amdgcn_cvt_pk_fp8_f32(f[6], f[7], w1, true);
    ((int*)dst)[i*2]   = w0;
    ((int*)dst)[i*2+1] = w1;
}

// ---------------------------------------------------------------- W_h+b_h -> bf16 [256][96]
__global__ __launch_bounds__(256) void k_prep_whp(
    const float* __restrict__ W_h, const float* __restrict__ b_h,
    short* __restrict__ dst)
{
    int i = blockIdx.x*256 + threadIdx.x;
    if (i >= 256*96) return;
    int n = i / 96, k = i - n*96;
    float v = (k < V_) ? W_h[(size_t)n*V_ + k] : (k == V_ ? b_h[n] : 0.f);
    dst[i] = f2bs(v);
}

// ---------------------------------------------------------------- coarse ffill scan: 32-t segments
__global__ __launch_bounds__(256) void k_scan_seg(
    const float* __restrict__ x, const float* __restrict__ mask,
    float* __restrict__ segVal, unsigned char* __restrict__ segHas)
{
    int gid = blockIdx.x*256 + threadIdx.x;      // 4*NPAIR exact (1424 blocks)
    int s = gid / NPAIR, pair = gid - s*NPAIR;
    int b = pair / V_, v = pair - b*V_;
    float val = 0.f; int has = 0;
    for (int j = 31; j >= 0; --j) {
        size_t idx = ((size_t)b*T_ + s*32 + j)*V_ + v;
        if (mask[idx] > 0.f) { val = x[idx]; has = 1; break; }
    }
    segVal[(size_t)s*NPAIR + pair] = val;
    segHas[(size_t)s*NPAIR + pair] = (unsigned char)has;
}

// ---------------------------------------------------------------- parallel impute: (pair, seg)
// grid (356, 4) x 256. Thread owns one pair for one 32-t segment.
__global__ __launch_bounds__(256) void k_impute_par(
    const float* __restrict__ x, const float* __restrict__ mask,
    const float* __restrict__ deltas, const float* __restrict__ meanset,
    const float* __restrict__ W_x, const float* __restrict__ b_x,
    const float* __restrict__ segVal, const unsigned char* __restrict__ segHas,
    float* __restrict__ ximp, unsigned char* __restrict__ xm8,
    float* __restrict__ num_part, float* __restrict__ den_part)
{
    int tid = threadIdx.x;
    int pair = blockIdx.x*256 + tid;             // < 91136 exact
    int sg = blockIdx.y;                         // 0..3
    int b = pair / V_, v = pair - b*V_;
    float wxd = W_x[v*V_ + v], bx = b_x[v], mnv = meanset[v];
    float last = 0.f;
    for (int s2 = 0; s2 < sg; ++s2)
        if (segHas[(size_t)s2*NPAIR + pair]) last = segVal[(size_t)s2*NPAIR + pair];
    int lane = tid & 63, wid = tid >> 6;
    int gw = blockIdx.x*4 + wid;                 // 0..1423
    size_t base = ((size_t)b*T_ + sg*32)*V_ + v;
    unsigned short* qp = (unsigned short*)xm8;
    for (int j = 0; j < 32; ++j) {
        float xt = x[base + j*V_], m = mask[base + j*V_], d = deltas[base + j*V_];
        float g = __expf(-fmaxf(fmaf(d, wxd, bx), 0.f));
        last = (m > 0.f) ? xt : last;
        float xu = g*last + (1.f-g)*mnv;
        float xh = m*xt + (1.f-m)*xu;
        ximp[base + j*V_] = xh;
        int pk = __builtin_amdgcn_cvt_pk_fp8_f32(xh, m, 0, false);
        qp[base + j*V_] = (unsigned short)(pk & 0xFFFF);
        float nv = fabsf(xt - xu)*m;
        float dv = m;
        for (int off = 32; off; off >>= 1) {
            nv += __shfl_down(nv, off);
            dv += __shfl_down(dv, off);
        }
        if (lane == 0) {
            num_part[(size_t)(sg*32 + j)*NW1 + gw] = nv;
            den_part[(size_t)(sg*32 + j)*NW1 + gw] = dv;
        }
    }
}

// ---------------------------------------------------------------- k_gates3: parallel gates+gamma
// grid (256, TC/4) x 512 thr. Block = 4 batch rows x 4 timesteps. Writes ushort4(r,z,n,gamma).
__global__ __launch_bounds__(512) void k_gates3(
    const unsigned char* __restrict__ xm8, const float* __restrict__ deltas,
    const unsigned char* __restrict__ wihT, const short* __restrict__ whp,
    unsigned short* __restrict__ gi4, int t0)
{
    __shared__ unsigned char xl[16*200] __attribute__((aligned(16)));
    __shared__ short dl2[16*104] __attribute__((aligned(16)));
    int tid = threadIdx.x, lane = tid & 63, wv = tid >> 6;
    int l15 = lane & 15, g8 = lane >> 4;
    int bg = blockIdx.x, ph = blockIdx.y;
    int tg = t0 + ph*4;

    for (int i = tid; i < 16*14; i += 512) {
        int r = i/14, k = 178 + (i - r*14);
        xl[r*200 + k] = (k == 178) ? 0x38 : 0;                   // fp8(1.0) bias col
    }
    for (int i = tid; i < 16*15; i += 512) {
        int r = i/15, k = 89 + (i - r*15);
        dl2[r*104 + k] = (k == 89) ? (short)0x3F80 : (short)0;   // bf16(1.0) bias col
    }
    for (int i = tid; i < 16*V_; i += 512) {
        int r = i / V_, v = i - r*V_;
        int b = bg*4 + (r >> 2), t = tg + (r & 3);
        unsigned short pk = *(const unsigned short*)(xm8 + ((size_t)(b*T_ + t)*V_ + v)*2);
        xl[r*200 + v]      = (unsigned char)(pk & 0xFF);
        xl[r*200 + V_ + v] = (unsigned char)(pk >> 8);
        dl2[r*104 + v]     = f2bs(deltas[((size_t)b*T_ + t)*V_ + v]);
    }
    __syncthreads();
    const long* wT = (const long*)wihT;
    #pragma unroll
    for (int s = 0; s < 2; ++s) {
        int cset = wv + s*8;
        size_t iw = (size_t)cset*1152 + g8*16 + l15;
        f32x4 ar = {0.f,0.f,0.f,0.f}, az = ar, an = ar, ga = ar;
        #pragma unroll
        for (int kt = 0; kt < 6; ++kt) {
            long a = *(const long*)&xl[l15*200 + kt*32 + g8*8];
            ar = __builtin_amdgcn_mfma_f32_16x16x32_fp8_fp8(a, wT[iw +       kt*64], ar, 0,0,0);
            az = __builtin_amdgcn_mfma_f32_16x16x32_fp8_fp8(a, wT[iw + 384 + kt*64], az, 0,0,0);
            an = __builtin_amdgcn_mfma_f32_16x16x32_fp8_fp8(a, wT[iw + 768 + kt*64], an, 0,0,0);
        }
        int cg = cset*16 + l15;
        #pragma unroll
        for (int kt = 0; kt < 3; ++kt) {
            bf16x8 da = *(const bf16x8*)&dl2[l15*104 + kt*32 + g8*8];
            bf16x8 gw = *(const bf16x8*)(whp + (size_t)cg*96 + kt*32 + g8*8);
            ga = __builtin_amdgcn_mfma_f32_16x16x32_bf16(da, gw, ga, 0,0,0);
        }
        #pragma unroll
        for (int rr = 0; rr < 4; ++rr) {
            int ltc = ph*4 + rr;
            u16x4 v;
            v[0] = (unsigned short)f2bs(ar[rr]);
            v[1] = (unsigned short)f2bs(az[rr]);
            v[2] = (unsigned short)f2bs(an[rr]);
            v[3] = (unsigned short)f2bs(__expf(-fmaxf(ga[rr], 0.f)));
            ((u16x4*)gi4)[(((size_t)ltc*256 + bg)*4 + g8)*256 + cg] = v;
        }
    }
}

// ---------------------------------------------------------------- k_recur: 16 waves, 1 col/lane
// (round-17 proven: lgkm-only barrier so gate prefetch survives; depth-2 prefetch)
__global__ __launch_bounds__(1024) void k_recur(
    const unsigned short* __restrict__ gi4, const unsigned char* __restrict__ whh8,
    const float* __restrict__ b_hh, const float* __restrict__ W_cls,
    const float* __restrict__ b_cls,
    float* __restrict__ hstate, float* __restrict__ yout, float* __restrict__ yscore,
    int TC, int first, int last)
{
    __shared__ unsigned char whL[256*256];
    __shared__ unsigned char hlds[2][4*272] __attribute__((aligned(16)));
    __shared__ float yred[4][16];

    int tid = threadIdx.x, lane = tid & 63, wv16 = tid >> 6;
    int l15 = lane & 15, g8 = lane >> 4;
    int blk = blockIdx.x;
    int c = wv16*16 + l15;

    #pragma unroll
    for (int it = 0; it < 8; ++it) {
        int idx = it*1024 + tid;
        int row = idx >> 5, j = idx & 31;
        long v = *(const long*)(whh8 + (size_t)row*256 + j*8);
        *(long*)&whL[row*256 + ((j*8) ^ ((row & 15) << 4))] = v;
    }
    i32x8 wz[2], wn[2];
    #pragma unroll
    for (int k2 = 0; k2 < 2; ++k2) {
        wz[k2] = *(const i32x8*)(whh8 + (size_t)(256 + c)*256 + k2*128 + g8*32);
        wn[k2] = *(const i32x8*)(whh8 + (size_t)(512 + c)*256 + k2*128 + g8*32);
    }
    #pragma unroll
    for (int k2 = 0; k2 < 2; ++k2) {
        #pragma unroll
        for (int j = 0; j < 8; ++j) {
            asm volatile("" : "+v"(wz[k2][j]));
            asm volatile("" : "+v"(wn[k2][j]));
        }
    }
    float bhr = b_hh[c], bhz = b_hh[256 + c], bhn = b_hh[512 + c];
    float h = first ? 0.f : hstate[(size_t)(blk*4 + g8)*H_ + c];
    __syncthreads();   // whL staged

    const u16x4* gp = (const u16x4*)gi4;
#define GIDX(LT) ((((size_t)(LT)*256 + blk)*4 + g8)*256 + c)
    u16x4 gv0 = gp[GIDX(0)];
    u16x4 gv1 = (TC > 1) ? gp[GIDX(1)] : gv0;
    int sw = l15 << 4;
    const unsigned char* wb = &whL[(size_t)c*256];

    for (int lt = 0; lt < TC; ++lt) {
        int cb = lt & 1;
        float hd = h * s2f(gv0[3]);
        int pk = __builtin_amdgcn_cvt_pk_fp8_f32(hd, hd, 0, false);
        hlds[cb][g8*272 + c] = (unsigned char)(pk & 0xFF);
        bar_lgkm();
        u16x4 gv2 = gv1;
        if (lt + 2 < TC) gv2 = gp[GIDX(lt + 2)];
        i32x8 A[2];
        #pragma unroll
        for (int k2 = 0; k2 < 2; ++k2) {
            const unsigned char* ap = &hlds[cb][(l15 >> 2)*272 + k2*128 + g8*32];
            i32x4 lo = *(const i32x4*)(ap);
            i32x4 hi = *(const i32x4*)(ap + 16);
            i32x8 a; a[0]=lo[0]; a[1]=lo[1]; a[2]=lo[2]; a[3]=lo[3];
                     a[4]=hi[0]; a[5]=hi[1]; a[6]=hi[2]; a[7]=hi[3];
            A[k2] = a;
        }
        f32x4 sr = {bhr,bhr,bhr,bhr};
        f32x4 sz = {bhz,bhz,bhz,bhz};
        f32x4 sn = {bhn,bhn,bhn,bhn};
        __builtin_amdgcn_s_setprio(1);
        #pragma unroll
        for (int k2 = 0; k2 < 2; ++k2) {
            int ob = k2*128 + g8*32;
            i32x4 blo = *(const i32x4*)(wb + ((ob     ) ^ sw));
            i32x4 bhi = *(const i32x4*)(wb + ((ob + 16) ^ sw));
            i32x8 b; b[0]=blo[0]; b[1]=blo[1]; b[2]=blo[2]; b[3]=blo[3];
                     b[4]=bhi[0]; b[5]=bhi[1]; b[6]=bhi[2]; b[7]=bhi[3];
            sr = __builtin_amdgcn_mfma_scale_f32_16x16x128_f8f6f4(A[k2], b,      sr, 0,0, 0,0x7F7F7F7F, 0,0x7F7F7F7F);
            sz = __builtin_amdgcn_mfma_scale_f32_16x16x128_f8f6f4(A[k2], wz[k2], sz, 0,0, 0,0x7F7F7F7F, 0,0x7F7F7F7F);
            sn = __builtin_amdgcn_mfma_scale_f32_16x16x128_f8f6f4(A[k2], wn[k2], sn, 0,0, 0,0x7F7F7F7F, 0,0x7F7F7F7F);
        }
        __builtin_amdgcn_s_setprio(0);
        float rg = sig_(s2f(gv0[0]) + sr[0]);
        float zg = sig_(s2f(gv0[1]) + sz[0]);
        float ng = tanh_(s2f(gv0[2]) + rg*sn[0]);
        h = (1.f - zg)*ng + zg*hd;
        gv0 = gv1; gv1 = gv2;
    }
#undef GIDX

    hstate[(size_t)(blk*4 + g8)*H_ + c] = h;

    if (last) {
        float pr = h * W_cls[c];
        pr += __shfl_xor(pr, 1);
        pr += __shfl_xor(pr, 2);
        pr += __shfl_xor(pr, 4);
        pr += __shfl_xor(pr, 8);
        if (l15 == 0) yred[g8][wv16] = pr;
        __syncthreads();
        if (tid < 4) {
            float sacc = b_cls[0];
            #pragma unroll
            for (int ww = 0; ww < 16; ++ww) sacc += yred[tid][ww];
            yout[blk*4 + tid]   = sacc;
            yscore[blk*4 + tid] = 1.f/(1.f+__expf(-sacc));
        }
    }
}

// ---------------------------------------------------------------- loss stage 1
__global__ __launch_bounds__(256) void k_loss_t(
    const float* __restrict__ num_part, const float* __restrict__ den_part,
    float* __restrict__ tpart)
{
    int t = blockIdx.x, tid = threadIdx.x;
    float num = 0.f, den = 0.f;
    for (int j = tid; j < NW1; j += 256) {
        num += num_part[(size_t)t*NW1 + j];
        den += den_part[(size_t)t*NW1 + j];
    }
    for (int off = 32; off; off >>= 1) { num += __shfl_down(num, off); den += __shfl_down(den, off); }
    __shared__ float sn[4], sd[4];
    int lane = tid & 63, wid = tid >> 6;
    if (lane == 0) { sn[wid] = num; sd[wid] = den; }
    __syncthreads();
    if (tid == 0) {
        float n = sn[0]+sn[1]+sn[2]+sn[3], d = sd[0]+sd[1]+sd[2]+sd[3];
        tpart[t] = n / (d + 1e-5f);
    }
}

// ---------------------------------------------------------------- loss stage 2
__global__ __launch_bounds__(128) void k_loss_final(
    const float* __restrict__ tpart, float* __restrict__ out_loss)
{
    int tid = threadIdx.x;
    float s = tpart[tid];
    for (int off = 32; off; off >>= 1) s += __shfl_down(s, off);
    __shared__ float sp[2];
    if ((tid&63)==0) sp[tid>>6] = s;
    __syncthreads();
    if (tid==0) out_loss[0] = sp[0] + sp[1];
}

static inline size_t al256(size_t x){ return (x + 255) & ~(size_t)255; }

extern "C" void kernel_launch(void* const* d_in, const int* in_sizes, int n_in,
                              void* d_out, int out_size, void* d_ws, size_t ws_size,
                              hipStream_t stream)
{
    const float* x      = (const float*)d_in[0];
    const float* mask   = (const float*)d_in[1];
    const float* deltas = (const float*)d_in[2];
    const float* meanset= (const float*)d_in[3];
    const float* W_h    = (const float*)d_in[4];
    const float* b_h    = (const float*)d_in[5];
    const float* W_x    = (const float*)d_in[6];
    const float* b_x    = (const float*)d_in[7];
    const float* W_ih   = (const float*)d_in[8];
    const float* b_ih   = (const float*)d_in[9];
    const float* W_hh   = (const float*)d_in[10];
    const float* b_hh   = (const float*)d_in[11];
    const float* W_cls  = (const float*)d_in[12];
    const float* b_cls  = (const float*)d_in[13];

    float* out    = (float*)d_out;
    float* ximp   = out;                        // B*T*V
    float* xloss  = out + (size_t)B_*T_*V_;     // 1
    float* yout   = xloss + 1;                  // B
    float* yscore = yout + B_;                  // B

    size_t off = 0;
    size_t off_whh8 = off; off = al256(off + (size_t)768*256);
    size_t off_wihT = off; off = al256(off + (size_t)768*192);
    size_t off_whp  = off; off = al256(off + (size_t)256*96*2);
    size_t off_sv   = off; off = al256(off + (size_t)4*NPAIR*4);
    size_t off_sh   = off; off = al256(off + (size_t)4*NPAIR);
    size_t off_xm8  = off; off = al256(off + (size_t)B_*T_*V_*2);
    size_t off_h    = off; off = al256(off + (size_t)B_*H_*4);
    size_t off_np   = off; off = al256(off + (size_t)T_*NW1*4);
    size_t off_dp   = off; off = al256(off + (size_t)T_*NW1*4);
    size_t off_tp   = off; off = al256(off + (size_t)T_*4);
    size_t off_gi4  = off;

    int tcShift = -1;
    for (int s = 7; s >= 2; --s) {
        size_t gib = (size_t)(1 << s) * 256 * 4 * 256 * 8;  // TC * bg * g8 * col * 8B
        if (off_gi4 + gib <= ws_size) { tcShift = s; break; }
    }
    if (tcShift < 0) return;
    int TC = 1 << tcShift;
    int NC = T_ / TC;

    char* ws = (char*)d_ws;
    unsigned char* whh8 = (unsigned char*)(ws + off_whh8);
    unsigned char* wihT = (unsigned char*)(ws + off_wihT);
    short* whp    = (short*)(ws + off_whp);
    float* segVal = (float*)(ws + off_sv);
    unsigned char* segHas = (unsigned char*)(ws + off_sh);
    unsigned char* xm8 = (unsigned char*)(ws + off_xm8);
    float* hstate = (float*)(ws + off_h);
    float* numpart= (float*)(ws + off_np);
    float* denpart= (float*)(ws + off_dp);
    float* tpart  = (float*)(ws + off_tp);
    unsigned short* gi4 = (unsigned short*)(ws + off_gi4);

    hipLaunchKernelGGL(k_cvt_fp8, dim3((768*256/4+255)/256), dim3(256), 0, stream, W_hh, whh8, 768*256);
    hipLaunchKernelGGL(k_prep_wih8, dim3((18432+255)/256), dim3(256), 0, stream, W_ih, b_ih, wihT);
    hipLaunchKernelGGL(k_prep_whp, dim3((256*96+255)/256), dim3(256), 0, stream, W_h, b_h, whp);
    hipLaunchKernelGGL(k_scan_seg, dim3(1424), dim3(256), 0, stream, x, mask, segVal, segHas);
    hipLaunchKernelGGL(k_impute_par, dim3(356, 4), dim3(256), 0, stream,
                       x, mask, deltas, meanset, W_x, b_x, segVal, segHas,
                       ximp, xm8, numpart, denpart);
    hipLaunchKernelGGL(k_loss_t, dim3(T_), dim3(256), 0, stream, numpart, denpart, tpart);
    hipLaunchKernelGGL(k_loss_final, dim3(1), dim3(128), 0, stream, tpart, xloss);

    for (int ci = 0; ci < NC; ++ci) {
        int t0 = ci * TC;
        hipLaunchKernelGGL(k_gates3, dim3(256, TC/4), dim3(512), 0, stream,
                           xm8, deltas, wihT, whp, gi4, t0);
        hipLaunchKernelGGL(k_recur, dim3(256), dim3(1024), 0, stream,
                           gi4, whh8, b_hh, W_cls, b_cls,
                           hstate, yout, yscore, TC, ci==0, ci==NC-1);
    }
}

// Round 19
// 347.746 us; speedup vs baseline: 1.0077x; 1.0077x over previous
//
#include <hip/hip_runtime.h>

#define B_  1024
#define T_  128
#define V_  89
#define H_  256
#define NB2 256
#define NPAIR 91136          // B_*V_
#define NW1  1424            // 356*4 loss waves

typedef __attribute__((ext_vector_type(8))) short bf16x8;
typedef __attribute__((ext_vector_type(4))) float f32x4;
typedef __attribute__((ext_vector_type(4))) unsigned short u16x4;
typedef __attribute__((ext_vector_type(8))) int i32x8;
typedef __attribute__((ext_vector_type(4))) int i32x4;

__device__ __forceinline__ short f2bs(float f){
    unsigned u = __float_as_uint(f);
    unsigned r = (u + 0x7FFFu + ((u>>16)&1u)) >> 16;
    return (short)r;
}
__device__ __forceinline__ float s2f(unsigned short s){
    return __uint_as_float(((unsigned)s) << 16);
}
__device__ __forceinline__ float sig_(float x){ return 1.f/(1.f+__expf(-x)); }
__device__ __forceinline__ float tanh_(float x){ return 2.f/(1.f+__expf(-2.f*x)) - 1.f; }
__device__ __forceinline__ void bar_lgkm(){
    asm volatile("s_waitcnt lgkmcnt(0)" ::: "memory");
    __builtin_amdgcn_s_barrier();
}

// ---------------------------------------------------------------- W_hh fp32 -> fp8 [768][256]
__global__ __launch_bounds__(256) void k_cvt_fp8(
    const float* __restrict__ src, unsigned char* __restrict__ dst, int n)
{
    int i = blockIdx.x*256 + threadIdx.x;
    if (i*4 >= n) return;
    float f0 = src[i*4+0], f1 = src[i*4+1], f2 = src[i*4+2], f3 = src[i*4+3];
    int w = __builtin_amdgcn_cvt_pk_fp8_f32(f0, f1, 0, false);
    w     = __builtin_amdgcn_cvt_pk_fp8_f32(f2, f3, w, true);
    ((int*)dst)[i] = w;
}

// ---------------------------------------------------------------- W_ih+b_ih -> fp8 frag-major
__global__ __launch_bounds__(256) void k_prep_wih8(
    const float* __restrict__ W_ih, const float* __restrict__ b_ih,
    unsigned char* __restrict__ dst)
{
    int i = blockIdx.x*256 + threadIdx.x;
    if (i >= 18432) return;
    int l15 = i & 15, t = i >> 4;
    int g8 = t & 3; t >>= 2;
    int kt = t % 6; t /= 6;
    int g = t % 3, WV = t / 3;
    int n = g*256 + WV*16 + l15;
    float f[8];
    #pragma unroll
    for (int j = 0; j < 8; ++j) {
        int k = kt*32 + g8*8 + j;
        f[j] = (k < 178) ? W_ih[(size_t)n*178 + k] : (k == 178 ? b_ih[n] : 0.f);
    }
    int w0 = __builtin_amdgcn_cvt_pk_fp8_f32(f[0], f[1], 0, false);
    w0     = __builtin_amdgcn_cvt_pk_fp8_f32(f[2], f[3], w0, true);
    int w1 = __builtin_amdgcn_cvt_pk_fp8_f32(f[4], f[5], 0, false);
    w1     = __builtin_amdgcn_cvt_pk_fp8_f32(f[6], f[7], w1, true);
    ((int*)dst)[i*2]   = w0;
    ((int*)dst)[i*2+1] = w1;
}

// ---------------------------------------------------------------- W_h+b_h -> bf16 [256][96]
__global__ __launch_bounds__(256) void k_prep_whp(
    const float* __restrict__ W_h, const float* __restrict__ b_h,
    short* __restrict__ dst)
{
    int i = blockIdx.x*256 + threadIdx.x;
    if (i >= 256*96) return;
    int n = i / 96, k = i - n*96;
    float v = (k < V_) ? W_h[(size_t)n*V_ + k] : (k == V_ ? b_h[n] : 0.f);
    dst[i] = f2bs(v);
}

// ---------------------------------------------------------------- coarse ffill scan: 32-t segments
__global__ __launch_bounds__(256) void k_scan_seg(
    const float* __restrict__ x, const float* __restrict__ mask,
    float* __restrict__ segVal, unsigned char* __restrict__ segHas)
{
    int gid = blockIdx.x*256 + threadIdx.x;      // 4*NPAIR exact (1424 blocks)
    int s = gid / NPAIR, pair = gid - s*NPAIR;
    int b = pair / V_, v = pair - b*V_;
    float val = 0.f; int has = 0;
    for (int j = 31; j >= 0; --j) {
        size_t idx = ((size_t)b*T_ + s*32 + j)*V_ + v;
        if (mask[idx] > 0.f) { val = x[idx]; has = 1; break; }
    }
    segVal[(size_t)s*NPAIR + pair] = val;
    segHas[(size_t)s*NPAIR + pair] = (unsigned char)has;
}

// ---------------------------------------------------------------- parallel impute: (pair, seg)
__global__ __launch_bounds__(256) void k_impute_par(
    const float* __restrict__ x, const float* __restrict__ mask,
    const float* __restrict__ deltas, const float* __restrict__ meanset,
    const float* __restrict__ W_x, const float* __restrict__ b_x,
    const float* __restrict__ segVal, const unsigned char* __restrict__ segHas,
    float* __restrict__ ximp, unsigned char* __restrict__ xm8,
    float* __restrict__ num_part, float* __restrict__ den_part)
{
    int tid = threadIdx.x;
    int pair = blockIdx.x*256 + tid;             // < 91136 exact
    int sg = blockIdx.y;                         // 0..3
    int b = pair / V_, v = pair - b*V_;
    float wxd = W_x[v*V_ + v], bx = b_x[v], mnv = meanset[v];
    float last = 0.f;
    for (int s2 = 0; s2 < sg; ++s2)
        if (segHas[(size_t)s2*NPAIR + pair]) last = segVal[(size_t)s2*NPAIR + pair];
    int lane = tid & 63, wid = tid >> 6;
    int gw = blockIdx.x*4 + wid;                 // 0..1423
    size_t base = ((size_t)b*T_ + sg*32)*V_ + v;
    unsigned short* qp = (unsigned short*)xm8;
    for (int j = 0; j < 32; ++j) {
        float xt = x[base + j*V_], m = mask[base + j*V_], d = deltas[base + j*V_];
        float g = __expf(-fmaxf(fmaf(d, wxd, bx), 0.f));
        last = (m > 0.f) ? xt : last;
        float xu = g*last + (1.f-g)*mnv;
        float xh = m*xt + (1.f-m)*xu;
        ximp[base + j*V_] = xh;
        int pk = __builtin_amdgcn_cvt_pk_fp8_f32(xh, m, 0, false);
        qp[base + j*V_] = (unsigned short)(pk & 0xFFFF);
        float nv = fabsf(xt - xu)*m;
        float dv = m;
        for (int off = 32; off; off >>= 1) {
            nv += __shfl_down(nv, off);
            dv += __shfl_down(dv, off);
        }
        if (lane == 0) {
            num_part[(size_t)(sg*32 + j)*NW1 + gw] = nv;
            den_part[(size_t)(sg*32 + j)*NW1 + gw] = dv;
        }
    }
}

// ---------------------------------------------------------------- k_gates3: 4 phases/block, pipelined
// grid (256, TC/16) x 512 thr. Block = 4 batch rows x 16 t (4 phases of 4 t).
__global__ __launch_bounds__(512) void k_gates3(
    const unsigned char* __restrict__ xm8, const float* __restrict__ deltas,
    const unsigned char* __restrict__ wihT, const short* __restrict__ whp,
    unsigned short* __restrict__ gi4, int t0)
{
    __shared__ unsigned char xl[16*200] __attribute__((aligned(16)));
    __shared__ short dl2[16*104] __attribute__((aligned(16)));
    int tid = threadIdx.x, lane = tid & 63, wv = tid >> 6;
    int l15 = lane & 15, g8 = lane >> 4;
    int bg = blockIdx.x, by = blockIdx.y;
    int tbase = t0 + by*16;

    for (int i = tid; i < 16*14; i += 512) {
        int r = i/14, k = 178 + (i - r*14);
        xl[r*200 + k] = (k == 178) ? 0x38 : 0;                   // fp8(1.0) bias col
    }
    for (int i = tid; i < 16*15; i += 512) {
        int r = i/15, k = 89 + (i - r*15);
        dl2[r*104 + k] = (k == 89) ? (short)0x3F80 : (short)0;   // bf16(1.0) bias col
    }

    // staging registers: up to 3 elements per thread
    int er0, ev0, er1, ev1, er2, ev2;
    bool ok1, ok2;
    {
        int i0 = tid;            er0 = i0 / V_; ev0 = i0 - er0*V_;
        int i1 = tid + 512; ok1 = i1 < 16*V_; er1 = ok1 ? i1 / V_ : 0; ev1 = ok1 ? (i1 - er1*V_) : 0;
        int i2 = tid + 1024; ok2 = i2 < 16*V_; er2 = ok2 ? i2 / V_ : 0; ev2 = ok2 ? (i2 - er2*V_) : 0;
    }
    unsigned short sp0 = 0, sp1 = 0, sp2 = 0;
    short sd0 = 0, sd1 = 0, sd2 = 0;

#define LOADP(P) do { \
        int tg = tbase + (P)*4; \
        { int b = bg*4 + (er0 >> 2), t = tg + (er0 & 3); \
          size_t idx = (size_t)(b*T_ + t)*V_ + ev0; \
          sp0 = *(const unsigned short*)(xm8 + idx*2); sd0 = f2bs(deltas[idx]); } \
        if (ok1) { int b = bg*4 + (er1 >> 2), t = tg + (er1 & 3); \
          size_t idx = (size_t)(b*T_ + t)*V_ + ev1; \
          sp1 = *(const unsigned short*)(xm8 + idx*2); sd1 = f2bs(deltas[idx]); } \
        if (ok2) { int b = bg*4 + (er2 >> 2), t = tg + (er2 & 3); \
          size_t idx = (size_t)(b*T_ + t)*V_ + ev2; \
          sp2 = *(const unsigned short*)(xm8 + idx*2); sd2 = f2bs(deltas[idx]); } \
    } while (0)

    LOADP(0);
    const long* wT = (const long*)wihT;

    for (int p = 0; p < 4; ++p) {
        // write staged regs to LDS
        xl[er0*200 + ev0]      = (unsigned char)(sp0 & 0xFF);
        xl[er0*200 + V_ + ev0] = (unsigned char)(sp0 >> 8);
        dl2[er0*104 + ev0]     = sd0;
        if (ok1) {
            xl[er1*200 + ev1]      = (unsigned char)(sp1 & 0xFF);
            xl[er1*200 + V_ + ev1] = (unsigned char)(sp1 >> 8);
            dl2[er1*104 + ev1]     = sd1;
        }
        if (ok2) {
            xl[er2*200 + ev2]      = (unsigned char)(sp2 & 0xFF);
            xl[er2*200 + V_ + ev2] = (unsigned char)(sp2 >> 8);
            dl2[er2*104 + ev2]     = sd2;
        }
        bar_lgkm();
        if (p < 3) LOADP(p+1);        // in flight under MFMA + stores
        #pragma unroll
        for (int s = 0; s < 2; ++s) {
            int cset = wv + s*8;
            size_t iw = (size_t)cset*1152 + g8*16 + l15;
            f32x4 ar = {0.f,0.f,0.f,0.f}, az = ar, an = ar, ga = ar;
            #pragma unroll
            for (int kt = 0; kt < 6; ++kt) {
                long a = *(const long*)&xl[l15*200 + kt*32 + g8*8];
                ar = __builtin_amdgcn_mfma_f32_16x16x32_fp8_fp8(a, wT[iw +       kt*64], ar, 0,0,0);
                az = __builtin_amdgcn_mfma_f32_16x16x32_fp8_fp8(a, wT[iw + 384 + kt*64], az, 0,0,0);
                an = __builtin_amdgcn_mfma_f32_16x16x32_fp8_fp8(a, wT[iw + 768 + kt*64], an, 0,0,0);
            }
            int cg = cset*16 + l15;
            #pragma unroll
            for (int kt = 0; kt < 3; ++kt) {
                bf16x8 da = *(const bf16x8*)&dl2[l15*104 + kt*32 + g8*8];
                bf16x8 gw = *(const bf16x8*)(whp + (size_t)cg*96 + kt*32 + g8*8);
                ga = __builtin_amdgcn_mfma_f32_16x16x32_bf16(da, gw, ga, 0,0,0);
            }
            #pragma unroll
            for (int rr = 0; rr < 4; ++rr) {
                int ltc = by*16 + p*4 + rr;
                u16x4 v;
                v[0] = (unsigned short)f2bs(ar[rr]);
                v[1] = (unsigned short)f2bs(az[rr]);
                v[2] = (unsigned short)f2bs(an[rr]);
                v[3] = (unsigned short)f2bs(__expf(-fmaxf(ga[rr], 0.f)));
                ((u16x4*)gi4)[(((size_t)ltc*256 + bg)*4 + g8)*256 + cg] = v;
            }
        }
        bar_lgkm();
    }
#undef LOADP
}

// ---------------------------------------------------------------- k_recur: all-reg weights
// 256 blocks x 1024 thr. Lane owns (batch g8, col c). r,z,n weights in 48 pinned VGPR.
// LDS = hlds only; lgkm-only barriers keep gate prefetch in flight.
__global__ __launch_bounds__(1024) void k_recur(
    const unsigned short* __restrict__ gi4, const unsigned char* __restrict__ whh8,
    const float* __restrict__ b_hh, const float* __restrict__ W_cls,
    const float* __restrict__ b_cls,
    float* __restrict__ hstate, float* __restrict__ yout, float* __restrict__ yscore,
    int TC, int first, int last)
{
    __shared__ unsigned char hlds[2][4*272] __attribute__((aligned(16)));
    __shared__ float yred[4][16];

    int tid = threadIdx.x, lane = tid & 63, wv16 = tid >> 6;
    int l15 = lane & 15, g8 = lane >> 4;
    int blk = blockIdx.x;
    int c = wv16*16 + l15;

    i32x8 wr[2], wz[2], wn[2];
    #pragma unroll
    for (int k2 = 0; k2 < 2; ++k2) {
        wr[k2] = *(const i32x8*)(whh8 + (size_t)(      c)*256 + k2*128 + g8*32);
        wz[k2] = *(const i32x8*)(whh8 + (size_t)(256 + c)*256 + k2*128 + g8*32);
        wn[k2] = *(const i32x8*)(whh8 + (size_t)(512 + c)*256 + k2*128 + g8*32);
    }
    #pragma unroll
    for (int k2 = 0; k2 < 2; ++k2) {
        #pragma unroll
        for (int j = 0; j < 8; ++j) {
            asm volatile("" : "+v"(wr[k2][j]));
            asm volatile("" : "+v"(wz[k2][j]));
            asm volatile("" : "+v"(wn[k2][j]));
        }
    }
    float bhr = b_hh[c], bhz = b_hh[256 + c], bhn = b_hh[512 + c];
    float h = first ? 0.f : hstate[(size_t)(blk*4 + g8)*H_ + c];

    const u16x4* gp = (const u16x4*)gi4;
#define GIDX(LT) ((((size_t)(LT)*256 + blk)*4 + g8)*256 + c)
    u16x4 gv0 = gp[GIDX(0)];
    u16x4 gv1 = (TC > 1) ? gp[GIDX(1)] : gv0;

    for (int lt = 0; lt < TC; ++lt) {
        int cb = lt & 1;
        float hd = h * s2f(gv0[3]);
        int pk = __builtin_amdgcn_cvt_pk_fp8_f32(hd, hd, 0, false);
        hlds[cb][g8*272 + c] = (unsigned char)(pk & 0xFF);
        bar_lgkm();
        u16x4 gv2 = gv1;
        if (lt + 2 < TC) gv2 = gp[GIDX(lt + 2)];
        i32x8 A[2];
        #pragma unroll
        for (int k2 = 0; k2 < 2; ++k2) {
            const unsigned char* ap = &hlds[cb][(l15 >> 2)*272 + k2*128 + g8*32];
            i32x4 lo = *(const i32x4*)(ap);
            i32x4 hi = *(const i32x4*)(ap + 16);
            i32x8 a; a[0]=lo[0]; a[1]=lo[1]; a[2]=lo[2]; a[3]=lo[3];
                     a[4]=hi[0]; a[5]=hi[1]; a[6]=hi[2]; a[7]=hi[3];
            A[k2] = a;
        }
        f32x4 sr = {bhr,bhr,bhr,bhr};
        f32x4 sz = {bhz,bhz,bhz,bhz};
        f32x4 sn = {bhn,bhn,bhn,bhn};
        __builtin_amdgcn_s_setprio(1);
        #pragma unroll
        for (int k2 = 0; k2 < 2; ++k2) {
            sr = __builtin_amdgcn_mfma_scale_f32_16x16x128_f8f6f4(A[k2], wr[k2], sr, 0,0, 0,0x7F7F7F7F, 0,0x7F7F7F7F);
            sz = __builtin_amdgcn_mfma_scale_f32_16x16x128_f8f6f4(A[k2], wz[k2], sz, 0,0, 0,0x7F7F7F7F, 0,0x7F7F7F7F);
            sn = __builtin_amdgcn_mfma_scale_f32_16x16x128_f8f6f4(A[k2], wn[k2], sn, 0,0, 0,0x7F7F7F7F, 0,0x7F7F7F7F);
        }
        __builtin_amdgcn_s_setprio(0);
        float rg = sig_(s2f(gv0[0]) + sr[0]);
        float zg = sig_(s2f(gv0[1]) + sz[0]);
        float ng = tanh_(s2f(gv0[2]) + rg*sn[0]);
        h = (1.f - zg)*ng + zg*hd;
        gv0 = gv1; gv1 = gv2;
    }
#undef GIDX

    hstate[(size_t)(blk*4 + g8)*H_ + c] = h;

    if (last) {
        float pr = h * W_cls[c];
        pr += __shfl_xor(pr, 1);
        pr += __shfl_xor(pr, 2);
        pr += __shfl_xor(pr, 4);
        pr += __shfl_xor(pr, 8);
        if (l15 == 0) yred[g8][wv16] = pr;
        __syncthreads();
        if (tid < 4) {
            float sacc = b_cls[0];
            #pragma unroll
            for (int ww = 0; ww < 16; ++ww) sacc += yred[tid][ww];
            yout[blk*4 + tid]   = sacc;
            yscore[blk*4 + tid] = 1.f/(1.f+__expf(-sacc));
        }
    }
}

// ---------------------------------------------------------------- loss stage 1
__global__ __launch_bounds__(256) void k_loss_t(
    const float* __restrict__ num_part, const float* __restrict__ den_part,
    float* __restrict__ tpart)
{
    int t = blockIdx.x, tid = threadIdx.x;
    float num = 0.f, den = 0.f;
    for (int j = tid; j < NW1; j += 256) {
        num += num_part[(size_t)t*NW1 + j];
        den += den_part[(size_t)t*NW1 + j];
    }
    for (int off = 32; off; off >>= 1) { num += __shfl_down(num, off); den += __shfl_down(den, off); }
    __shared__ float sn[4], sd[4];
    int lane = tid & 63, wid = tid >> 6;
    if (lane == 0) { sn[wid] = num; sd[wid] = den; }
    __syncthreads();
    if (tid == 0) {
        float n = sn[0]+sn[1]+sn[2]+sn[3], d = sd[0]+sd[1]+sd[2]+sd[3];
        tpart[t] = n / (d + 1e-5f);
    }
}

// ---------------------------------------------------------------- loss stage 2
__global__ __launch_bounds__(128) void k_loss_final(
    const float* __restrict__ tpart, float* __restrict__ out_loss)
{
    int tid = threadIdx.x;
    float s = tpart[tid];
    for (int off = 32; off; off >>= 1) s += __shfl_down(s, off);
    __shared__ float sp[2];
    if ((tid&63)==0) sp[tid>>6] = s;
    __syncthreads();
    if (tid==0) out_loss[0] = sp[0] + sp[1];
}

static inline size_t al256(size_t x){ return (x + 255) & ~(size_t)255; }

extern "C" void kernel_launch(void* const* d_in, const int* in_sizes, int n_in,
                              void* d_out, int out_size, void* d_ws, size_t ws_size,
                              hipStream_t stream)
{
    const float* x      = (const float*)d_in[0];
    const float* mask   = (const float*)d_in[1];
    const float* deltas = (const float*)d_in[2];
    const float* meanset= (const float*)d_in[3];
    const float* W_h    = (const float*)d_in[4];
    const float* b_h    = (const float*)d_in[5];
    const float* W_x    = (const float*)d_in[6];
    const float* b_x    = (const float*)d_in[7];
    const float* W_ih   = (const float*)d_in[8];
    const float* b_ih   = (const float*)d_in[9];
    const float* W_hh   = (const float*)d_in[10];
    const float* b_hh   = (const float*)d_in[11];
    const float* W_cls  = (const float*)d_in[12];
    const float* b_cls  = (const float*)d_in[13];

    float* out    = (float*)d_out;
    float* ximp   = out;                        // B*T*V
    float* xloss  = out + (size_t)B_*T_*V_;     // 1
    float* yout   = xloss + 1;                  // B
    float* yscore = yout + B_;                  // B

    size_t off = 0;
    size_t off_whh8 = off; off = al256(off + (size_t)768*256);
    size_t off_wihT = off; off = al256(off + (size_t)768*192);
    size_t off_whp  = off; off = al256(off + (size_t)256*96*2);
    size_t off_sv   = off; off = al256(off + (size_t)4*NPAIR*4);
    size_t off_sh   = off; off = al256(off + (size_t)4*NPAIR);
    size_t off_xm8  = off; off = al256(off + (size_t)B_*T_*V_*2);
    size_t off_h    = off; off = al256(off + (size_t)B_*H_*4);
    size_t off_np   = off; off = al256(off + (size_t)T_*NW1*4);
    size_t off_dp   = off; off = al256(off + (size_t)T_*NW1*4);
    size_t off_tp   = off; off = al256(off + (size_t)T_*4);
    size_t off_gi4  = off;

    int tcShift = -1;
    for (int s = 7; s >= 4; --s) {
        size_t gib = (size_t)(1 << s) * 256 * 4 * 256 * 8;  // TC * bg * g8 * col * 8B
        if (off_gi4 + gib <= ws_size) { tcShift = s; break; }
    }
    if (tcShift < 0) return;
    int TC = 1 << tcShift;
    int NC = T_ / TC;

    char* ws = (char*)d_ws;
    unsigned char* whh8 = (unsigned char*)(ws + off_whh8);
    unsigned char* wihT = (unsigned char*)(ws + off_wihT);
    short* whp    = (short*)(ws + off_whp);
    float* segVal = (float*)(ws + off_sv);
    unsigned char* segHas = (unsigned char*)(ws + off_sh);
    unsigned char* xm8 = (unsigned char*)(ws + off_xm8);
    float* hstate = (float*)(ws + off_h);
    float* numpart= (float*)(ws + off_np);
    float* denpart= (float*)(ws + off_dp);
    float* tpart  = (float*)(ws + off_tp);
    unsigned short* gi4 = (unsigned short*)(ws + off_gi4);

    hipLaunchKernelGGL(k_cvt_fp8, dim3((768*256/4+255)/256), dim3(256), 0, stream, W_hh, whh8, 768*256);
    hipLaunchKernelGGL(k_prep_wih8, dim3((18432+255)/256), dim3(256), 0, stream, W_ih, b_ih, wihT);
    hipLaunchKernelGGL(k_prep_whp, dim3((256*96+255)/256), dim3(256), 0, stream, W_h, b_h, whp);
    hipLaunchKernelGGL(k_scan_seg, dim3(1424), dim3(256), 0, stream, x, mask, segVal, segHas);
    hipLaunchKernelGGL(k_impute_par, dim3(356, 4), dim3(256), 0, stream,
                       x, mask, deltas, meanset, W_x, b_x, segVal, segHas,
                       ximp, xm8, numpart, denpart);
    hipLaunchKernelGGL(k_loss_t, dim3(T_), dim3(256), 0, stream, numpart, denpart, tpart);
    hipLaunchKernelGGL(k_loss_final, dim3(1), dim3(128), 0, stream, tpart, xloss);

    for (int ci = 0; ci < NC; ++ci) {
        int t0 = ci * TC;
        hipLaunchKernelGGL(k_gates3, dim3(256, TC/16), dim3(512), 0, stream,
                           xm8, deltas, wihT, whp, gi4, t0);
        hipLaunchKernelGGL(k_recur, dim3(256), dim3(1024), 0, stream,
                           gi4, whh8, b_hh, W_cls, b_cls,
                           hstate, yout, yscore, TC, ci==0, ci==NC-1);
    }
}

// Round 20
// 273.813 us; speedup vs baseline: 1.2798x; 1.2700x over previous
//
#include <hip/hip_runtime.h>

#define B_  1024
#define T_  128
#define V_  89
#define H_  256
#define NB2 256

typedef __attribute__((ext_vector_type(8))) short bf16x8;
typedef __attribute__((ext_vector_type(4))) float f32x4;
typedef __attribute__((ext_vector_type(4))) unsigned short u16x4;
typedef __attribute__((ext_vector_type(8))) int i32x8;
typedef __attribute__((ext_vector_type(4))) int i32x4;

__device__ __forceinline__ short f2bs(float f){
    unsigned u = __float_as_uint(f);
    unsigned r = (u + 0x7FFFu + ((u>>16)&1u)) >> 16;
    return (short)r;
}
__device__ __forceinline__ float s2f(unsigned short s){
    return __uint_as_float(((unsigned)s) << 16);
}
__device__ __forceinline__ float sig_(float x){ return 1.f/(1.f+__expf(-x)); }
__device__ __forceinline__ float tanh_(float x){ return 2.f/(1.f+__expf(-2.f*x)) - 1.f; }
__device__ __forceinline__ void bar_lgkm(){
    asm volatile("s_waitcnt lgkmcnt(0)" ::: "memory");
    __builtin_amdgcn_s_barrier();
}

// ---------------------------------------------------------------- W_hh fp32 -> fp8 [768][256]
__global__ __launch_bounds__(256) void k_cvt_fp8(
    const float* __restrict__ src, unsigned char* __restrict__ dst, int n)
{
    int i = blockIdx.x*256 + threadIdx.x;
    if (i*4 >= n) return;
    float f0 = src[i*4+0], f1 = src[i*4+1], f2 = src[i*4+2], f3 = src[i*4+3];
    int w = __builtin_amdgcn_cvt_pk_fp8_f32(f0, f1, 0, false);
    w     = __builtin_amdgcn_cvt_pk_fp8_f32(f2, f3, w, true);
    ((int*)dst)[i] = w;
}

// ---------------------------------------------------------------- W_ih+b_ih -> fp8 frag-major
// chunk idx = (((WV*3+g)*6+kt)*4+g8)*16+l15; 8 fp8 of row n=g*256+WV*16+l15, k=kt*32+g8*8..+7
// (k: 0..177 = W_ih, 178 = bias, else 0)
__global__ __launch_bounds__(256) void k_prep_wih8(
    const float* __restrict__ W_ih, const float* __restrict__ b_ih,
    unsigned char* __restrict__ dst)
{
    int i = blockIdx.x*256 + threadIdx.x;
    if (i >= 18432) return;
    int l15 = i & 15, t = i >> 4;
    int g8 = t & 3; t >>= 2;
    int kt = t % 6; t /= 6;
    int g = t % 3, WV = t / 3;
    int n = g*256 + WV*16 + l15;
    float f[8];
    #pragma unroll
    for (int j = 0; j < 8; ++j) {
        int k = kt*32 + g8*8 + j;
        f[j] = (k < 178) ? W_ih[(size_t)n*178 + k] : (k == 178 ? b_ih[n] : 0.f);
    }
    int w0 = __builtin_amdgcn_cvt_pk_fp8_f32(f[0], f[1], 0, false);
    w0     = __builtin_amdgcn_cvt_pk_fp8_f32(f[2], f[3], w0, true);
    int w1 = __builtin_amdgcn_cvt_pk_fp8_f32(f[4], f[5], 0, false);
    w1     = __builtin_amdgcn_cvt_pk_fp8_f32(f[6], f[7], w1, true);
    ((int*)dst)[i*2]   = w0;
    ((int*)dst)[i*2+1] = w1;
}

// ---------------------------------------------------------------- W_h+b_h -> bf16 [256][96]
__global__ __launch_bounds__(256) void k_prep_whp(
    const float* __restrict__ W_h, const float* __restrict__ b_h,
    short* __restrict__ dst)
{
    int i = blockIdx.x*256 + threadIdx.x;
    if (i >= 256*96) return;
    int n = i / 96, k = i - n*96;
    float v = (k < V_) ? W_h[(size_t)n*V_ + k] : (k == V_ ? b_h[n] : 0.f);
    dst[i] = f2bs(v);
}

// ---------------------------------------------------------------- k_prep: impute + gates + gamma
// 256 blocks x 512 thr. Block = 4 batch rows, phases of 4 t. Writes ushort4(r,z,n,gamma) bf16
// at word idx (((ltc*256+blk)*4+g8)*256 + col). (round-12 proven: 76 us/chunk)
__global__ __launch_bounds__(512) void k_prep(
    const float* __restrict__ x, const float* __restrict__ mask,
    const float* __restrict__ deltas, const float* __restrict__ meanset,
    const float* __restrict__ W_x, const float* __restrict__ b_x,
    const unsigned char* __restrict__ wihT, const short* __restrict__ whp,
    float* __restrict__ ximp, float* __restrict__ lastst,
    float* __restrict__ numpart, float* __restrict__ denpart,
    unsigned short* __restrict__ gi4, int t0, int TC, int first)
{
    __shared__ unsigned char xl[16*200] __attribute__((aligned(16)));
    __shared__ short dl2[16*104] __attribute__((aligned(16)));
    __shared__ float lossn[4][360], lossd[4][360];
    int tid = threadIdx.x, lane = tid & 63, wv = tid >> 6;
    int l15 = lane & 15, g8 = lane >> 4;
    int blk = blockIdx.x;

    for (int i = tid; i < 16*22; i += 512) {
        int r = i/22, k = 178 + (i - r*22);
        xl[r*200 + k] = (k == 178) ? 0x38 : 0;          // fp8(1.0) bias col
    }
    for (int i = tid; i < 16*15; i += 512) {
        int r = i/15, k = 89 + (i - r*15);
        dl2[r*104 + k] = (k == 89) ? (short)0x3F80 : (short)0;  // bf16(1.0) bias col
    }
    bool own = tid < 4*V_;
    int r_o = tid / V_, v_o = tid - r_o*V_, b_o = blk*4 + r_o;
    float wxd = 0.f, bx = 0.f, mnv = 0.f, lastv = 0.f;
    if (own) {
        wxd = W_x[v_o*V_ + v_o]; bx = b_x[v_o]; mnv = meanset[v_o];
        lastv = first ? 0.f : lastst[(size_t)b_o*V_ + v_o];
    }
    const long* wT = (const long*)wihT;

    int nph = TC >> 2;
    for (int p = 0; p < nph; ++p) {
        int tg = t0 + p*4;
        __syncthreads();               // prior phase's GEMM reads complete
        if (own) {
            const float* xb = x      + ((size_t)b_o*T_ + tg)*V_ + v_o;
            const float* mb = mask   + ((size_t)b_o*T_ + tg)*V_ + v_o;
            const float* db = deltas + ((size_t)b_o*T_ + tg)*V_ + v_o;
            float xv[4], mv[4], dv[4];
            #pragma unroll
            for (int lt = 0; lt < 4; ++lt) {
                xv[lt] = xb[lt*V_]; mv[lt] = mb[lt*V_]; dv[lt] = db[lt*V_];
            }
            #pragma unroll
            for (int lt = 0; lt < 4; ++lt) {
                float xt = xv[lt], m = mv[lt], d = dv[lt];
                float gx = __expf(-fmaxf(fmaf(d, wxd, bx), 0.f));
                lastv = (m > 0.f) ? xt : lastv;
                float xu = gx*lastv + (1.f-gx)*mnv;
                float xh = m*xt + (1.f-m)*xu;
                ximp[((size_t)b_o*T_ + tg + lt)*V_ + v_o] = xh;
                int mr = r_o*4 + lt;
                int pk = __builtin_amdgcn_cvt_pk_fp8_f32(xh, m, 0, false);
                xl[mr*200 + v_o]      = (unsigned char)(pk & 0xFF);
                xl[mr*200 + V_ + v_o] = (unsigned char)((pk >> 8) & 0xFF);
                dl2[mr*104 + v_o]     = f2bs(d);
                lossn[lt][tid] = fabsf(xt - xu)*m;
                lossd[lt][tid] = m;
            }
        }
        __syncthreads();
        if (tid < 64) {
            int lt = tid >> 4, part = tid & 15;
            float n = 0.f, ds = 0.f;
            for (int j = part; j < 4*V_; j += 16) { n += lossn[lt][j]; ds += lossd[lt][j]; }
            n += __shfl_xor(n, 1); ds += __shfl_xor(ds, 1);
            n += __shfl_xor(n, 2); ds += __shfl_xor(ds, 2);
            n += __shfl_xor(n, 4); ds += __shfl_xor(ds, 4);
            n += __shfl_xor(n, 8); ds += __shfl_xor(ds, 8);
            if (part == 0) {
                numpart[(size_t)(tg+lt)*NB2 + blk] = n;
                denpart[(size_t)(tg+lt)*NB2 + blk] = ds;
            }
        }
        #pragma unroll
        for (int s = 0; s < 2; ++s) {
            int cset = wv + s*8;
            size_t iw = (size_t)cset*1152 + g8*16 + l15;
            f32x4 ar = {0.f,0.f,0.f,0.f}, az = ar, an = ar, ga = ar;
            #pragma unroll
            for (int kt = 0; kt < 6; ++kt) {
                long a = *(const long*)&xl[l15*200 + kt*32 + g8*8];
                ar = __builtin_amdgcn_mfma_f32_16x16x32_fp8_fp8(a, wT[iw +       kt*64], ar, 0,0,0);
                az = __builtin_amdgcn_mfma_f32_16x16x32_fp8_fp8(a, wT[iw + 384 + kt*64], az, 0,0,0);
                an = __builtin_amdgcn_mfma_f32_16x16x32_fp8_fp8(a, wT[iw + 768 + kt*64], an, 0,0,0);
            }
            int cg = cset*16 + l15;
            #pragma unroll
            for (int kt = 0; kt < 3; ++kt) {
                bf16x8 da = *(const bf16x8*)&dl2[l15*104 + kt*32 + g8*8];
                bf16x8 gw = *(const bf16x8*)(whp + (size_t)cg*96 + kt*32 + g8*8);
                ga = __builtin_amdgcn_mfma_f32_16x16x32_bf16(da, gw, ga, 0,0,0);
            }
            #pragma unroll
            for (int rr = 0; rr < 4; ++rr) {
                int ltc = p*4 + rr;
                u16x4 v;
                v[0] = (unsigned short)f2bs(ar[rr]);
                v[1] = (unsigned short)f2bs(az[rr]);
                v[2] = (unsigned short)f2bs(an[rr]);
                v[3] = (unsigned short)f2bs(__expf(-fmaxf(ga[rr], 0.f)));
                ((u16x4*)gi4)[(((size_t)ltc*256 + blk)*4 + g8)*256 + cg] = v;
            }
        }
    }
    if (own) lastst[(size_t)b_o*V_ + v_o] = lastv;
}

// ---------------------------------------------------------------- k_recur: 16 waves, 1 col/lane
// (round-17 proven: whL swizzled LDS r-gate + reg z/n + lgkm-only barrier + depth-2 prefetch)
__global__ __launch_bounds__(1024) void k_recur(
    const unsigned short* __restrict__ gi4, const unsigned char* __restrict__ whh8,
    const float* __restrict__ b_hh, const float* __restrict__ W_cls,
    const float* __restrict__ b_cls,
    float* __restrict__ hstate, float* __restrict__ yout, float* __restrict__ yscore,
    int TC, int first, int last)
{
    __shared__ unsigned char whL[256*256];
    __shared__ unsigned char hlds[2][4*272] __attribute__((aligned(16)));
    __shared__ float yred[4][16];

    int tid = threadIdx.x, lane = tid & 63, wv16 = tid >> 6;
    int l15 = lane & 15, g8 = lane >> 4;
    int blk = blockIdx.x;
    int c = wv16*16 + l15;

    #pragma unroll
    for (int it = 0; it < 8; ++it) {
        int idx = it*1024 + tid;
        int row = idx >> 5, j = idx & 31;
        long v = *(const long*)(whh8 + (size_t)row*256 + j*8);
        *(long*)&whL[row*256 + ((j*8) ^ ((row & 15) << 4))] = v;
    }
    i32x8 wz[2], wn[2];
    #pragma unroll
    for (int k2 = 0; k2 < 2; ++k2) {
        wz[k2] = *(const i32x8*)(whh8 + (size_t)(256 + c)*256 + k2*128 + g8*32);
        wn[k2] = *(const i32x8*)(whh8 + (size_t)(512 + c)*256 + k2*128 + g8*32);
    }
    #pragma unroll
    for (int k2 = 0; k2 < 2; ++k2) {
        #pragma unroll
        for (int j = 0; j < 8; ++j) {
            asm volatile("" : "+v"(wz[k2][j]));
            asm volatile("" : "+v"(wn[k2][j]));
        }
    }
    float bhr = b_hh[c], bhz = b_hh[256 + c], bhn = b_hh[512 + c];
    float h = first ? 0.f : hstate[(size_t)(blk*4 + g8)*H_ + c];
    __syncthreads();   // whL staged

    const u16x4* gp = (const u16x4*)gi4;
#define GIDX(LT) ((((size_t)(LT)*256 + blk)*4 + g8)*256 + c)
    u16x4 gv0 = gp[GIDX(0)];
    u16x4 gv1 = (TC > 1) ? gp[GIDX(1)] : gv0;
    int sw = l15 << 4;
    const unsigned char* wb = &whL[(size_t)c*256];

    for (int lt = 0; lt < TC; ++lt) {
        int cb = lt & 1;
        float hd = h * s2f(gv0[3]);
        int pk = __builtin_amdgcn_cvt_pk_fp8_f32(hd, hd, 0, false);
        hlds[cb][g8*272 + c] = (unsigned char)(pk & 0xFF);
        bar_lgkm();
        u16x4 gv2 = gv1;
        if (lt + 2 < TC) gv2 = gp[GIDX(lt + 2)];
        i32x8 A[2];
        #pragma unroll
        for (int k2 = 0; k2 < 2; ++k2) {
            const unsigned char* ap = &hlds[cb][(l15 >> 2)*272 + k2*128 + g8*32];
            i32x4 lo = *(const i32x4*)(ap);
            i32x4 hi = *(const i32x4*)(ap + 16);
            i32x8 a; a[0]=lo[0]; a[1]=lo[1]; a[2]=lo[2]; a[3]=lo[3];
                     a[4]=hi[0]; a[5]=hi[1]; a[6]=hi[2]; a[7]=hi[3];
            A[k2] = a;
        }
        f32x4 sr = {bhr,bhr,bhr,bhr};
        f32x4 sz = {bhz,bhz,bhz,bhz};
        f32x4 sn = {bhn,bhn,bhn,bhn};
        __builtin_amdgcn_s_setprio(1);
        #pragma unroll
        for (int k2 = 0; k2 < 2; ++k2) {
            int ob = k2*128 + g8*32;
            i32x4 blo = *(const i32x4*)(wb + ((ob     ) ^ sw));
            i32x4 bhi = *(const i32x4*)(wb + ((ob + 16) ^ sw));
            i32x8 b; b[0]=blo[0]; b[1]=blo[1]; b[2]=blo[2]; b[3]=blo[3];
                     b[4]=bhi[0]; b[5]=bhi[1]; b[6]=bhi[2]; b[7]=bhi[3];
            sr = __builtin_amdgcn_mfma_scale_f32_16x16x128_f8f6f4(A[k2], b,      sr, 0,0, 0,0x7F7F7F7F, 0,0x7F7F7F7F);
            sz = __builtin_amdgcn_mfma_scale_f32_16x16x128_f8f6f4(A[k2], wz[k2], sz, 0,0, 0,0x7F7F7F7F, 0,0x7F7F7F7F);
            sn = __builtin_amdgcn_mfma_scale_f32_16x16x128_f8f6f4(A[k2], wn[k2], sn, 0,0, 0,0x7F7F7F7F, 0,0x7F7F7F7F);
        }
        __builtin_amdgcn_s_setprio(0);
        float rg = sig_(s2f(gv0[0]) + sr[0]);
        float zg = sig_(s2f(gv0[1]) + sz[0]);
        float ng = tanh_(s2f(gv0[2]) + rg*sn[0]);
        h = (1.f - zg)*ng + zg*hd;
        gv0 = gv1; gv1 = gv2;
    }
#undef GIDX

    hstate[(size_t)(blk*4 + g8)*H_ + c] = h;

    if (last) {
        float pr = h * W_cls[c];
        pr += __shfl_xor(pr, 1);
        pr += __shfl_xor(pr, 2);
        pr += __shfl_xor(pr, 4);
        pr += __shfl_xor(pr, 8);
        if (l15 == 0) yred[g8][wv16] = pr;
        __syncthreads();
        if (tid < 4) {
            float sacc = b_cls[0];
            #pragma unroll
            for (int ww = 0; ww < 16; ++ww) sacc += yred[tid][ww];
            yout[blk*4 + tid]   = sacc;
            yscore[blk*4 + tid] = 1.f/(1.f+__expf(-sacc));
        }
    }
}

// ---------------------------------------------------------------- loss stage 1
__global__ __launch_bounds__(256) void k_loss_t(
    const float* __restrict__ numpart, const float* __restrict__ denpart,
    float* __restrict__ tpart)
{
    int t = blockIdx.x, tid = threadIdx.x;
    float n = numpart[(size_t)t*NB2 + tid];
    float d = denpart[(size_t)t*NB2 + tid];
    for (int off = 32; off; off >>= 1) { n += __shfl_down(n, off); d += __shfl_down(d, off); }
    __shared__ float sn[4], sd[4];
    int lane = tid & 63, wid = tid >> 6;
    if (lane == 0) { sn[wid] = n; sd[wid] = d; }
    __syncthreads();
    if (tid == 0) {
        float nn = sn[0]+sn[1]+sn[2]+sn[3], dd = sd[0]+sd[1]+sd[2]+sd[3];
        tpart[t] = nn / (dd + 1e-5f);
    }
}

// ---------------------------------------------------------------- loss stage 2
__global__ __launch_bounds__(128) void k_loss_final(
    const float* __restrict__ tpart, float* __restrict__ out_loss)
{
    int tid = threadIdx.x;
    float s = tpart[tid];
    for (int off = 32; off; off >>= 1) s += __shfl_down(s, off);
    __shared__ float sp[2];
    if ((tid&63)==0) sp[tid>>6] = s;
    __syncthreads();
    if (tid==0) out_loss[0] = sp[0] + sp[1];
}

static inline size_t al256(size_t x){ return (x + 255) & ~(size_t)255; }

extern "C" void kernel_launch(void* const* d_in, const int* in_sizes, int n_in,
                              void* d_out, int out_size, void* d_ws, size_t ws_size,
                              hipStream_t stream)
{
    const float* x      = (const float*)d_in[0];
    const float* mask   = (const float*)d_in[1];
    const float* deltas = (const float*)d_in[2];
    const float* meanset= (const float*)d_in[3];
    const float* W_h    = (const float*)d_in[4];
    const float* b_h    = (const float*)d_in[5];
    const float* W_x    = (const float*)d_in[6];
    const float* b_x    = (const float*)d_in[7];
    const float* W_ih   = (const float*)d_in[8];
    const float* b_ih   = (const float*)d_in[9];
    const float* W_hh   = (const float*)d_in[10];
    const float* b_hh   = (const float*)d_in[11];
    const float* W_cls  = (const float*)d_in[12];
    const float* b_cls  = (const float*)d_in[13];

    float* out    = (float*)d_out;
    float* ximp   = out;                        // B*T*V
    float* xloss  = out + (size_t)B_*T_*V_;     // 1
    float* yout   = xloss + 1;                  // B
    float* yscore = yout + B_;                  // B

    size_t off = 0;
    size_t off_whh8 = off; off = al256(off + (size_t)768*256);
    size_t off_wihT = off; off = al256(off + (size_t)768*192);
    size_t off_whp  = off; off = al256(off + (size_t)256*96*2);
    size_t off_last = off; off = al256(off + (size_t)B_*V_*4);
    size_t off_h    = off; off = al256(off + (size_t)B_*H_*4);
    size_t off_np   = off; off = al256(off + (size_t)T_*NB2*4);
    size_t off_dp   = off; off = al256(off + (size_t)T_*NB2*4);
    size_t off_tp   = off; off = al256(off + (size_t)T_*4);
    size_t off_gi4  = off;

    int tcShift = -1;
    for (int s = 7; s >= 2; --s) {
        size_t gib = (size_t)(1 << s) * 256 * 4 * 256 * 8;  // TC * blk * g8 * col * 8B
        if (off_gi4 + gib <= ws_size) { tcShift = s; break; }
    }
    if (tcShift < 0) return;
    int TC = 1 << tcShift;
    int NC = T_ / TC;

    char* ws = (char*)d_ws;
    unsigned char* whh8 = (unsigned char*)(ws + off_whh8);
    unsigned char* wihT = (unsigned char*)(ws + off_wihT);
    short* whp    = (short*)(ws + off_whp);
    float* lastst = (float*)(ws + off_last);
    float* hstate = (float*)(ws + off_h);
    float* numpart= (float*)(ws + off_np);
    float* denpart= (float*)(ws + off_dp);
    float* tpart  = (float*)(ws + off_tp);
    unsigned short* gi4 = (unsigned short*)(ws + off_gi4);

    hipLaunchKernelGGL(k_cvt_fp8, dim3((768*256/4+255)/256), dim3(256), 0, stream, W_hh, whh8, 768*256);
    hipLaunchKernelGGL(k_prep_wih8, dim3((18432+255)/256), dim3(256), 0, stream, W_ih, b_ih, wihT);
    hipLaunchKernelGGL(k_prep_whp, dim3((256*96+255)/256), dim3(256), 0, stream, W_h, b_h, whp);

    for (int ci = 0; ci < NC; ++ci) {
        int t0 = ci * TC;
        hipLaunchKernelGGL(k_prep, dim3(256), dim3(512), 0, stream,
                           x, mask, deltas, meanset, W_x, b_x, wihT, whp,
                           ximp, lastst, numpart, denpart, gi4, t0, TC, ci==0);
        hipLaunchKernelGGL(k_recur, dim3(256), dim3(1024), 0, stream,
                           gi4, whh8, b_hh, W_cls, b_cls,
                           hstate, yout, yscore, TC, ci==0, ci==NC-1);
    }
    hipLaunchKernelGGL(k_loss_t, dim3(T_), dim3(256), 0, stream, numpart, denpart, tpart);
    hipLaunchKernelGGL(k_loss_final, dim3(1), dim3(128), 0, stream, tpart, xloss);
}